// Round 22
// baseline (688.902 us; speedup 1.0000x reference)
//
#include <hip/hip_runtime.h>
#include <hip/hip_bf16.h>

typedef __attribute__((ext_vector_type(8))) short s16x8;
typedef __attribute__((ext_vector_type(4))) float f32x4;

typedef __attribute__((address_space(1))) void v_as1;
typedef __attribute__((address_space(3))) void v_as3;

__device__ __forceinline__ void gload16(const void* g, void* l) {
    __builtin_amdgcn_global_load_lds((const v_as1*)g, (v_as3*)l, 16, 0, 0);
}

__device__ __forceinline__ unsigned short f2bf(float f) {
    unsigned u = __float_as_uint(f);
    unsigned r = (u + 0x7FFFu + ((u >> 16) & 1u)) >> 16;
    return (unsigned short)r;
}
__device__ __forceinline__ float frombf(unsigned short u) {
    return __uint_as_float(((unsigned)u) << 16);
}

// exact-GELU: 0.5*v*(1+erf(v/sqrt2)) via A&S 7.1.26 erf (abs err ~1.5e-7 << bf16 rounding).
__device__ __forceinline__ float gelu_fast(float v) {
    float ax = fabsf(v) * 0.70710678118f;    // |v|/sqrt(2)
    float t = __builtin_amdgcn_rcpf(fmaf(0.3275911f, ax, 1.f));
    float poly = t * fmaf(t, fmaf(t, fmaf(t, fmaf(t, 1.061405429f, -1.453152027f),
                                          1.421413741f), -0.284496736f), 0.254829592f);
    float e = exp2f(ax * ax * -1.44269504089f);   // exp(-v^2/2)
    float er = fmaf(-poly, e, 1.f);               // erf(|v|/sqrt2)
    er = copysignf(er, v);
    return 0.5f * v * (1.f + er);
}

// ---------------- prep kernels ----------------
__global__ void prep_w1(const float* __restrict__ W1, unsigned short* __restrict__ w1t) {
    int idx = blockIdx.x * 256 + threadIdx.x;           // over 768*512
    if (idx >= 768 * 512) return;
    int n = idx >> 9, k = idx & 511;
    int g = (n >= 384) ? 1 : 0;
    int d = n - g * 384;
    w1t[idx] = f2bf(W1[((long)g * 512 + k) * 384 + d]);
}

__global__ void prep_w2(const float* __restrict__ W2, unsigned short* __restrict__ w2t) {
    int idx = blockIdx.x * 256 + threadIdx.x;           // over 1024*384
    if (idx >= 1024 * 384) return;
    int n = idx / 384, k = idx % 384;
    int g = (n >= 512) ? 1 : 0;
    int d = n - g * 512;
    w2t[idx] = f2bf(W2[((long)g * 384 + k) * 512 + d]);
}

// coef[v*17+w] = offdiag sym coeff; coef[289+v] = diag coeff.
__global__ void prep_adj(const float* __restrict__ adj, const float* __restrict__ A2a,
                         const float* __restrict__ A2b, float* __restrict__ coef1,
                         float* __restrict__ coef2) {
    int t = threadIdx.x;
    if (t < 289) {
        int v = t / 17, w = t % 17;
        int tt = w * 17 + v;
        float s1 = 0.5f * (adj[t] + A2a[t] + adj[tt] + A2a[tt]);
        float s2 = 0.5f * (adj[t] + A2b[t] + adj[tt] + A2b[tt]);
        coef1[t] = (v == w) ? 0.f : s1;
        coef2[t] = (v == w) ? 0.f : s2;
        if (v == w) { coef1[289 + v] = s1; coef2[289 + v] = s2; }
    }
}

// ---------------- LN1: x(f32,[rows][512]) -> y(bf16) ----------------
__global__ __launch_bounds__(256) void ln1_kernel(const float* __restrict__ x,
                                                  const float* __restrict__ g,
                                                  const float* __restrict__ b,
                                                  unsigned short* __restrict__ y, int rows) {
    int wave = threadIdx.x >> 6, lane = threadIdx.x & 63;
    long row = (long)blockIdx.x * 4 + wave;
    if (row >= rows) return;
    const float4* xr = (const float4*)(x + row * 512);
    float4 v0 = xr[lane];
    float4 v1 = xr[lane + 64];
    float s = v0.x + v0.y + v0.z + v0.w + v1.x + v1.y + v1.z + v1.w;
    float q = v0.x * v0.x + v0.y * v0.y + v0.z * v0.z + v0.w * v0.w +
              v1.x * v1.x + v1.y * v1.y + v1.z * v1.z + v1.w * v1.w;
    #pragma unroll
    for (int off = 32; off; off >>= 1) { s += __shfl_xor(s, off); q += __shfl_xor(q, off); }
    float mean = s * (1.f / 512.f);
    float var  = q * (1.f / 512.f) - mean * mean;
    float rstd = rsqrtf(var + 1e-5f);
    const float4* gr = (const float4*)g;
    const float4* br = (const float4*)b;
    ushort4* yr = (ushort4*)(y + row * 512);
    #pragma unroll
    for (int i = 0; i < 2; ++i) {
        float4 vv = i ? v1 : v0;
        float4 gg = gr[lane + 64 * i];
        float4 bb = br[lane + 64 * i];
        ushort4 o;
        o.x = f2bf((vv.x - mean) * rstd * gg.x + bb.x);
        o.y = f2bf((vv.y - mean) * rstd * gg.y + bb.y);
        o.z = f2bf((vv.z - mean) * rstd * gg.z + bb.z);
        o.w = f2bf((vv.w - mean) * rstd * gg.w + bb.w);
        yr[lane + 64 * i] = o;
    }
}

// ---------------- GEMM: C[M][Ncols] = A[M][K](bf16) * Bt[Ncols][K]^T, bf16 out ----------------
// BM=256 x BN=128 tile, 512 threads (8 waves, 4x2). Single-buffer 2-barrier skeleton (R15-proven);
// XOR-swizzled LDS (linear dest, pre-swizzled global source, swizzled read), bijective XCD remap.
// Scalar C-writes (LDS-bounce epilogue raced under graph replay and was slower — R20).
__global__ __launch_bounds__(512) void gemm_bt_kernel(const unsigned short* __restrict__ A,
                                                      const unsigned short* __restrict__ Bt,
                                                      unsigned short* __restrict__ C,
                                                      int K, int Ncols, int NBX) {
    __shared__ __align__(16) unsigned short As[256 * 64];
    __shared__ __align__(16) unsigned short Bs[128 * 64];
    const int t = threadIdx.x;
    const int lane = t & 63;
    const int w = t >> 6;           // 0..7
    const int wr = w >> 1;          // 0..3 (row strip of 64)
    const int wc = w & 1;           // 0..1 (col strip of 64)

    const int nwg = gridDim.x;
    const int q = nwg >> 3, r = nwg & 7;
    const int xcd = blockIdx.x & 7, pos = blockIdx.x >> 3;
    const int wgid = (xcd < r ? xcd * (q + 1) : r * (q + 1) + (xcd - r) * q) + pos;
    const int bx = wgid % NBX;
    const int by = wgid / NBX;
    const long row0 = (long)by * 256;
    const long col0 = (long)bx * 128;

    const int lm = lane & 15;
    const int g4 = lane >> 4;
    const int swz0 = ((g4 ^ (lm & 7)) * 8);
    const int swz1 = (((g4 + 4) ^ (lm & 7)) * 8);

    f32x4 acc[4][4];
    #pragma unroll
    for (int m = 0; m < 4; ++m)
        #pragma unroll
        for (int n = 0; n < 4; ++n) acc[m][n] = (f32x4)0.f;

    const int srow = t >> 3;                 // 0..63
    const int sslot = (t & 7) ^ (srow & 7);
    const unsigned short* aBase = A + (row0 + srow) * K + sslot * 8;
    const unsigned short* bBase = Bt + (col0 + srow) * K + sslot * 8;
    unsigned short* aDst = &As[w * 512];     // + rr*4096 per pass
    unsigned short* bDst = &Bs[w * 512];

    const int ktiles = K >> 6;
    for (int kt = 0; kt < ktiles; ++kt) {
        const long ko = (long)kt * 64;
        __syncthreads();
        #pragma unroll
        for (int rr = 0; rr < 4; ++rr)
            gload16(aBase + (long)(rr * 64) * K + ko, aDst + rr * 4096);
        #pragma unroll
        for (int rr = 0; rr < 2; ++rr)
            gload16(bBase + (long)(rr * 64) * K + ko, bDst + rr * 4096);
        __syncthreads();
        #pragma unroll
        for (int kk = 0; kk < 2; ++kk) {
            const int so = kk ? swz1 : swz0;
            s16x8 af[4], bfv[4];
            #pragma unroll
            for (int m = 0; m < 4; ++m)
                af[m] = *(const s16x8*)&As[(wr * 64 + m * 16 + lm) * 64 + so];
            #pragma unroll
            for (int n = 0; n < 4; ++n)
                bfv[n] = *(const s16x8*)&Bs[(wc * 64 + n * 16 + lm) * 64 + so];
            #pragma unroll
            for (int m = 0; m < 4; ++m)
                #pragma unroll
                for (int n = 0; n < 4; ++n)
                    acc[m][n] = __builtin_amdgcn_mfma_f32_16x16x32_bf16(af[m], bfv[n], acc[m][n], 0, 0, 0);
        }
    }
    const int r4 = (lane >> 4) * 4;
    #pragma unroll
    for (int m = 0; m < 4; ++m) {
        #pragma unroll
        for (int j = 0; j < 4; ++j) {
            long grow = row0 + wr * 64 + m * 16 + r4 + j;
            unsigned short* crow = C + grow * Ncols + col0 + wc * 64 + lm;
            #pragma unroll
            for (int n = 0; n < 4; ++n) crow[n * 16] = f2bf(acc[m][n][j]);
        }
    }
}

// ---------------- mix1 + bias + gelu (register-streamed): h[17b][768] -> z[17b][384] ----------------
// block = 384 threads = 2 batches; 192 threads per batch, thread owns 2 d-cols.
// No LDS; coefficients via uniform scalar loads (SGPR invariant).
__global__ __launch_bounds__(384) void mixgelu_kernel(const unsigned short* __restrict__ h,
                                                      const float* __restrict__ M1,
                                                      const float* __restrict__ coef,
                                                      const float* __restrict__ bias,
                                                      unsigned short* __restrict__ z) {
    const int t = threadIdx.x;
    const int half = t / 192;            // 0 or 1
    const int tt = t - half * 192;       // 0..191
    const int d0 = tt * 2;
    const long b = blockIdx.x * 2 + half;
    const unsigned short* hb = h + b * 17 * 768;

    float ax[17], ay[17];
    const float bx = bias[d0], by = bias[d0 + 1];
    #pragma unroll
    for (int v = 0; v < 17; ++v) {
        float dg = coef[289 + v];
        float2 m = *(const float2*)(M1 + v * 384 + d0);
        ushort2 hv = *(const ushort2*)(hb + v * 768 + d0);
        ax[v] = dg * m.x * frombf(hv.x) + bx;
        ay[v] = dg * m.y * frombf(hv.y) + by;
    }
    #pragma unroll
    for (int w = 0; w < 17; ++w) {
        float2 m = *(const float2*)(M1 + w * 384 + d0);
        ushort2 hw = *(const ushort2*)(hb + w * 768 + 384 + d0);
        float px = m.x * frombf(hw.x);
        float py = m.y * frombf(hw.y);
        #pragma unroll
        for (int v = 0; v < 17; ++v) {
            float c = coef[v * 17 + w];
            ax[v] += c * px;
            ay[v] += c * py;
        }
    }
    unsigned short* zb = z + b * 17 * 384 + d0;
    #pragma unroll
    for (int v = 0; v < 17; ++v) {
        float gx = gelu_fast(ax[v]);
        float gy = gelu_fast(ay[v]);
        ushort2 o; o.x = f2bf(gx); o.y = f2bf(gy);
        *(ushort2*)(zb + v * 384) = o;
    }
}

// ---------------- final: mix2 + bias + LN + residual + gate ----------------
// block = 512 threads = 2 batches (waves 0-3 batch 0, waves 4-7 batch 1); per-thread work
// byte-identical to the proven VGPR-56 form (2 cols, scalar ax/ay, SGPR coef). Doubles
// waves/block to probe the block-residency occupancy cap.
__global__ __launch_bounds__(512) void final_kernel(const unsigned short* __restrict__ h2,
                                                    const float* __restrict__ x,
                                                    const float* __restrict__ bone,
                                                    const float* __restrict__ M2,
                                                    const float* __restrict__ coef,
                                                    const float* __restrict__ bias2,
                                                    const float* __restrict__ g2,
                                                    const float* __restrict__ b2,
                                                    float* __restrict__ out) {
    __shared__ float gate[2][17];
    __shared__ float red[2][17][8];  // [batch][v][wave]=sum, [batch][v][4+wave]=sumsq
    const int t = threadIdx.x, lane = t & 63, wave = t >> 6;   // wave 0..7
    const int hb_ = wave >> 2;       // batch within block
    const int wv = wave & 3;         // wave within batch (0..3)
    const int d0 = (t & 255) * 2;
    const long b = (long)blockIdx.x * 2 + hb_;

    #pragma unroll
    for (int v0 = 0; v0 < 20; v0 += 4) {
        int v = v0 + wv;
        if (v < 17) {
            float s = bone[(b * 17 + v) * 192 + lane];
            #pragma unroll
            for (int off = 32; off; off >>= 1) s += __shfl_xor(s, off);
            if (lane == 0) gate[hb_][v] = 1.f / (1.f + expf(-s * (0.01f / 64.f)));
        }
    }

    const unsigned short* hb = h2 + b * 17 * 1024;
    float ax[17], ay[17];
    const float bx = bias2[d0], by = bias2[d0 + 1];
    #pragma unroll
    for (int v = 0; v < 17; ++v) {
        float dg = coef[289 + v];
        float2 m = *(const float2*)(M2 + v * 512 + d0);
        ushort2 hv = *(const ushort2*)(hb + v * 1024 + d0);
        ax[v] = dg * m.x * frombf(hv.x) + bx;
        ay[v] = dg * m.y * frombf(hv.y) + by;
    }
    #pragma unroll
    for (int w = 0; w < 17; ++w) {
        float2 m = *(const float2*)(M2 + w * 512 + d0);
        ushort2 hw = *(const ushort2*)(hb + w * 1024 + 512 + d0);
        float px = m.x * frombf(hw.x);
        float py = m.y * frombf(hw.y);
        #pragma unroll
        for (int v = 0; v < 17; ++v) {
            float c = coef[v * 17 + w];     // uniform -> s_load, SGPR operand
            ax[v] += c * px;
            ay[v] += c * py;
        }
    }
    #pragma unroll
    for (int v = 0; v < 17; ++v) {
        float s = ax[v] + ay[v];
        float q = ax[v] * ax[v] + ay[v] * ay[v];
        #pragma unroll
        for (int off = 32; off; off >>= 1) { s += __shfl_xor(s, off); q += __shfl_xor(q, off); }
        if (lane == 0) { red[hb_][v][wv] = s; red[hb_][v][4 + wv] = q; }
    }
    __syncthreads();
    const float2 gg = *(const float2*)(g2 + d0);
    const float2 bb = *(const float2*)(b2 + d0);
    const float* xb = x + b * 17 * 512 + d0;
    float* ob = out + b * 17 * 512 + d0;
    #pragma unroll
    for (int v = 0; v < 17; ++v) {
        float s = red[hb_][v][0] + red[hb_][v][1] + red[hb_][v][2] + red[hb_][v][3];
        float q = red[hb_][v][4] + red[hb_][v][5] + red[hb_][v][6] + red[hb_][v][7];
        float mean = s * (1.f / 512.f);
        float rstd = rsqrtf(q * (1.f / 512.f) - mean * mean + 1e-5f);
        const bool endj = (v == 3 || v == 6 || v == 10 || v == 13 || v == 16);
        float scale = endj ? (1.f + 0.03f * gate[hb_][v]) : 1.f;
        float2 xv = *(const float2*)(xb + v * 512);
        float ox = (xv.x + (ax[v] - mean) * rstd * gg.x + bb.x) * scale;
        float oy = (xv.y + (ay[v] - mean) * rstd * gg.y + bb.y) * scale;
        *(float2*)(ob + v * 512) = make_float2(ox, oy);
    }
}

// ---------------- launch ----------------
extern "C" void kernel_launch(void* const* d_in, const int* in_sizes, int n_in,
                              void* d_out, int out_size, void* d_ws, size_t ws_size,
                              hipStream_t stream) {
    const float* x     = (const float*)d_in[0];
    const float* bone  = (const float*)d_in[1];
    const float* adj   = (const float*)d_in[2];
    const float* g1    = (const float*)d_in[3];
    const float* b1    = (const float*)d_in[4];
    const float* W1    = (const float*)d_in[5];
    const float* M1    = (const float*)d_in[6];
    const float* A21   = (const float*)d_in[7];
    const float* bias1 = (const float*)d_in[8];
    const float* W2    = (const float*)d_in[9];
    const float* M2    = (const float*)d_in[10];
    const float* A22   = (const float*)d_in[11];
    const float* bias2 = (const float*)d_in[12];
    const float* g2    = (const float*)d_in[13];
    const float* b2    = (const float*)d_in[14];
    float* out = (float*)d_out;

    char* ws = (char*)d_ws;
    size_t off = 0;
    auto alloc = [&](size_t bytes) -> char* {
        char* p = ws + off;
        off = (off + bytes + 255) & ~(size_t)255;
        return p;
    };
    unsigned short* w1t = (unsigned short*)alloc(768 * 512 * 2);
    unsigned short* w2t = (unsigned short*)alloc(1024 * 384 * 2);
    float* coef1 = (float*)alloc(306 * 4);
    float* coef2 = (float*)alloc(306 * 4);
    size_t fixed = off;

    int nc = 32;
    const int cands[6] = {1, 2, 4, 8, 16, 32};
    for (int ci = 0; ci < 6; ++ci) {
        size_t Bc = 8192 / cands[ci];
        size_t need = fixed + Bc * 17 * (512 + 768 + 384 + 1024) * 2 + 4 * 256;
        if (need <= ws_size) { nc = cands[ci]; break; }
    }
    long Bc = 8192 / nc;
    unsigned short* y  = (unsigned short*)alloc(Bc * 17 * 512 * 2);
    unsigned short* h  = (unsigned short*)alloc(Bc * 17 * 768 * 2);
    unsigned short* z  = (unsigned short*)alloc(Bc * 17 * 384 * 2);
    unsigned short* h2 = (unsigned short*)alloc(Bc * 17 * 1024 * 2);

    prep_w1<<<(768 * 512 + 255) / 256, 256, 0, stream>>>(W1, w1t);
    prep_w2<<<(1024 * 384 + 255) / 256, 256, 0, stream>>>(W2, w2t);
    prep_adj<<<1, 320, 0, stream>>>(adj, A21, A22, coef1, coef2);

    int rows = (int)(Bc * 17);
    int nby = rows / 256;
    for (int c = 0; c < nc; ++c) {
        long rb = (long)c * rows;
        ln1_kernel<<<rows / 4, 256, 0, stream>>>(x + rb * 512, g1, b1, y, rows);
        gemm_bt_kernel<<<6 * nby, 512, 0, stream>>>(y, w1t, h, 512, 768, 6);
        mixgelu_kernel<<<Bc / 2, 384, 0, stream>>>(h, M1, coef1, bias1, z);
        gemm_bt_kernel<<<8 * nby, 512, 0, stream>>>(z, w2t, h2, 384, 1024, 8);
        final_kernel<<<Bc / 2, 512, 0, stream>>>(h2, x + rb * 512, bone + rb * 192, M2, coef2,
                                                 bias2, g2, b2, out + rb * 512);
    }
}

// Round 23
// 675.848 us; speedup vs baseline: 1.0193x; 1.0193x over previous
//
#include <hip/hip_runtime.h>
#include <hip/hip_bf16.h>

typedef __attribute__((ext_vector_type(8))) short s16x8;
typedef __attribute__((ext_vector_type(4))) float f32x4;

typedef __attribute__((address_space(1))) void v_as1;
typedef __attribute__((address_space(3))) void v_as3;

__device__ __forceinline__ void gload16(const void* g, void* l) {
    __builtin_amdgcn_global_load_lds((const v_as1*)g, (v_as3*)l, 16, 0, 0);
}

__device__ __forceinline__ unsigned short f2bf(float f) {
    unsigned u = __float_as_uint(f);
    unsigned r = (u + 0x7FFFu + ((u >> 16) & 1u)) >> 16;
    return (unsigned short)r;
}
__device__ __forceinline__ float frombf(unsigned short u) {
    return __uint_as_float(((unsigned)u) << 16);
}

// exact-GELU: 0.5*v*(1+erf(v/sqrt2)) via A&S 7.1.26 erf (abs err ~1.5e-7 << bf16 rounding).
__device__ __forceinline__ float gelu_fast(float v) {
    float ax = fabsf(v) * 0.70710678118f;    // |v|/sqrt(2)
    float t = __builtin_amdgcn_rcpf(fmaf(0.3275911f, ax, 1.f));
    float poly = t * fmaf(t, fmaf(t, fmaf(t, fmaf(t, 1.061405429f, -1.453152027f),
                                          1.421413741f), -0.284496736f), 0.254829592f);
    float e = exp2f(ax * ax * -1.44269504089f);   // exp(-v^2/2)
    float er = fmaf(-poly, e, 1.f);               // erf(|v|/sqrt2)
    er = copysignf(er, v);
    return 0.5f * v * (1.f + er);
}

// ---------------- prep kernels ----------------
__global__ void prep_w1(const float* __restrict__ W1, unsigned short* __restrict__ w1t) {
    int idx = blockIdx.x * 256 + threadIdx.x;           // over 768*512
    if (idx >= 768 * 512) return;
    int n = idx >> 9, k = idx & 511;
    int g = (n >= 384) ? 1 : 0;
    int d = n - g * 384;
    w1t[idx] = f2bf(W1[((long)g * 512 + k) * 384 + d]);
}

__global__ void prep_w2(const float* __restrict__ W2, unsigned short* __restrict__ w2t) {
    int idx = blockIdx.x * 256 + threadIdx.x;           // over 1024*384
    if (idx >= 1024 * 384) return;
    int n = idx / 384, k = idx % 384;
    int g = (n >= 512) ? 1 : 0;
    int d = n - g * 512;
    w2t[idx] = f2bf(W2[((long)g * 384 + k) * 512 + d]);
}

// coef[v*17+w] = offdiag sym coeff; coef[289+v] = diag coeff.
__global__ void prep_adj(const float* __restrict__ adj, const float* __restrict__ A2a,
                         const float* __restrict__ A2b, float* __restrict__ coef1,
                         float* __restrict__ coef2) {
    int t = threadIdx.x;
    if (t < 289) {
        int v = t / 17, w = t % 17;
        int tt = w * 17 + v;
        float s1 = 0.5f * (adj[t] + A2a[t] + adj[tt] + A2a[tt]);
        float s2 = 0.5f * (adj[t] + A2b[t] + adj[tt] + A2b[tt]);
        coef1[t] = (v == w) ? 0.f : s1;
        coef2[t] = (v == w) ? 0.f : s2;
        if (v == w) { coef1[289 + v] = s1; coef2[289 + v] = s2; }
    }
}

// ---------------- LN1: x(f32,[rows][512]) -> y(bf16) ----------------
__global__ __launch_bounds__(256) void ln1_kernel(const float* __restrict__ x,
                                                  const float* __restrict__ g,
                                                  const float* __restrict__ b,
                                                  unsigned short* __restrict__ y, int rows) {
    int wave = threadIdx.x >> 6, lane = threadIdx.x & 63;
    long row = (long)blockIdx.x * 4 + wave;
    if (row >= rows) return;
    const float4* xr = (const float4*)(x + row * 512);
    float4 v0 = xr[lane];
    float4 v1 = xr[lane + 64];
    float s = v0.x + v0.y + v0.z + v0.w + v1.x + v1.y + v1.z + v1.w;
    float q = v0.x * v0.x + v0.y * v0.y + v0.z * v0.z + v0.w * v0.w +
              v1.x * v1.x + v1.y * v1.y + v1.z * v1.z + v1.w * v1.w;
    #pragma unroll
    for (int off = 32; off; off >>= 1) { s += __shfl_xor(s, off); q += __shfl_xor(q, off); }
    float mean = s * (1.f / 512.f);
    float var  = q * (1.f / 512.f) - mean * mean;
    float rstd = rsqrtf(var + 1e-5f);
    const float4* gr = (const float4*)g;
    const float4* br = (const float4*)b;
    ushort4* yr = (ushort4*)(y + row * 512);
    #pragma unroll
    for (int i = 0; i < 2; ++i) {
        float4 vv = i ? v1 : v0;
        float4 gg = gr[lane + 64 * i];
        float4 bb = br[lane + 64 * i];
        ushort4 o;
        o.x = f2bf((vv.x - mean) * rstd * gg.x + bb.x);
        o.y = f2bf((vv.y - mean) * rstd * gg.y + bb.y);
        o.z = f2bf((vv.z - mean) * rstd * gg.z + bb.z);
        o.w = f2bf((vv.w - mean) * rstd * gg.w + bb.w);
        yr[lane + 64 * i] = o;
    }
}

// ---------------- GEMM: C[M][Ncols] = A[M][K](bf16) * Bt[Ncols][K]^T, bf16 out ----------------
// BM=256 x BN=128 tile, 512 threads (8 waves, 4x2). Single-buffer 2-barrier skeleton (R15-proven);
// XOR-swizzled LDS (linear dest, pre-swizzled global source, swizzled read), bijective XCD remap.
// Scalar C-writes (LDS-bounce epilogue raced under graph replay and was slower — R20).
__global__ __launch_bounds__(512) void gemm_bt_kernel(const unsigned short* __restrict__ A,
                                                      const unsigned short* __restrict__ Bt,
                                                      unsigned short* __restrict__ C,
                                                      int K, int Ncols, int NBX) {
    __shared__ __align__(16) unsigned short As[256 * 64];
    __shared__ __align__(16) unsigned short Bs[128 * 64];
    const int t = threadIdx.x;
    const int lane = t & 63;
    const int w = t >> 6;           // 0..7
    const int wr = w >> 1;          // 0..3 (row strip of 64)
    const int wc = w & 1;           // 0..1 (col strip of 64)

    const int nwg = gridDim.x;
    const int q = nwg >> 3, r = nwg & 7;
    const int xcd = blockIdx.x & 7, pos = blockIdx.x >> 3;
    const int wgid = (xcd < r ? xcd * (q + 1) : r * (q + 1) + (xcd - r) * q) + pos;
    const int bx = wgid % NBX;
    const int by = wgid / NBX;
    const long row0 = (long)by * 256;
    const long col0 = (long)bx * 128;

    const int lm = lane & 15;
    const int g4 = lane >> 4;
    const int swz0 = ((g4 ^ (lm & 7)) * 8);
    const int swz1 = (((g4 + 4) ^ (lm & 7)) * 8);

    f32x4 acc[4][4];
    #pragma unroll
    for (int m = 0; m < 4; ++m)
        #pragma unroll
        for (int n = 0; n < 4; ++n) acc[m][n] = (f32x4)0.f;

    const int srow = t >> 3;                 // 0..63
    const int sslot = (t & 7) ^ (srow & 7);
    const unsigned short* aBase = A + (row0 + srow) * K + sslot * 8;
    const unsigned short* bBase = Bt + (col0 + srow) * K + sslot * 8;
    unsigned short* aDst = &As[w * 512];     // + rr*4096 per pass
    unsigned short* bDst = &Bs[w * 512];

    const int ktiles = K >> 6;
    for (int kt = 0; kt < ktiles; ++kt) {
        const long ko = (long)kt * 64;
        __syncthreads();
        #pragma unroll
        for (int rr = 0; rr < 4; ++rr)
            gload16(aBase + (long)(rr * 64) * K + ko, aDst + rr * 4096);
        #pragma unroll
        for (int rr = 0; rr < 2; ++rr)
            gload16(bBase + (long)(rr * 64) * K + ko, bDst + rr * 4096);
        __syncthreads();
        #pragma unroll
        for (int kk = 0; kk < 2; ++kk) {
            const int so = kk ? swz1 : swz0;
            s16x8 af[4], bfv[4];
            #pragma unroll
            for (int m = 0; m < 4; ++m)
                af[m] = *(const s16x8*)&As[(wr * 64 + m * 16 + lm) * 64 + so];
            #pragma unroll
            for (int n = 0; n < 4; ++n)
                bfv[n] = *(const s16x8*)&Bs[(wc * 64 + n * 16 + lm) * 64 + so];
            #pragma unroll
            for (int m = 0; m < 4; ++m)
                #pragma unroll
                for (int n = 0; n < 4; ++n)
                    acc[m][n] = __builtin_amdgcn_mfma_f32_16x16x32_bf16(af[m], bfv[n], acc[m][n], 0, 0, 0);
        }
    }
    const int r4 = (lane >> 4) * 4;
    #pragma unroll
    for (int m = 0; m < 4; ++m) {
        #pragma unroll
        for (int j = 0; j < 4; ++j) {
            long grow = row0 + wr * 64 + m * 16 + r4 + j;
            unsigned short* crow = C + grow * Ncols + col0 + wc * 64 + lm;
            #pragma unroll
            for (int n = 0; n < 4; ++n) crow[n * 16] = f2bf(acc[m][n][j]);
        }
    }
}

// ---------------- mix1 + bias + gelu (register-streamed): h[17b][768] -> z[17b][384] ----------------
// block = 384 threads = 2 batches; 192 threads per batch, thread owns 2 d-cols.
// No LDS; coefficients via uniform scalar loads (SGPR invariant).
__global__ __launch_bounds__(384) void mixgelu_kernel(const unsigned short* __restrict__ h,
                                                      const float* __restrict__ M1,
                                                      const float* __restrict__ coef,
                                                      const float* __restrict__ bias,
                                                      unsigned short* __restrict__ z) {
    const int t = threadIdx.x;
    const int half = t / 192;            // 0 or 1
    const int tt = t - half * 192;       // 0..191
    const int d0 = tt * 2;
    const long b = blockIdx.x * 2 + half;
    const unsigned short* hb = h + b * 17 * 768;

    float ax[17], ay[17];
    const float bx = bias[d0], by = bias[d0 + 1];
    #pragma unroll
    for (int v = 0; v < 17; ++v) {
        float dg = coef[289 + v];
        float2 m = *(const float2*)(M1 + v * 384 + d0);
        ushort2 hv = *(const ushort2*)(hb + v * 768 + d0);
        ax[v] = dg * m.x * frombf(hv.x) + bx;
        ay[v] = dg * m.y * frombf(hv.y) + by;
    }
    #pragma unroll
    for (int w = 0; w < 17; ++w) {
        float2 m = *(const float2*)(M1 + w * 384 + d0);
        ushort2 hw = *(const ushort2*)(hb + w * 768 + 384 + d0);
        float px = m.x * frombf(hw.x);
        float py = m.y * frombf(hw.y);
        #pragma unroll
        for (int v = 0; v < 17; ++v) {
            float c = coef[v * 17 + w];
            ax[v] += c * px;
            ay[v] += c * py;
        }
    }
    unsigned short* zb = z + b * 17 * 384 + d0;
    #pragma unroll
    for (int v = 0; v < 17; ++v) {
        float gx = gelu_fast(ax[v]);
        float gy = gelu_fast(ay[v]);
        ushort2 o; o.x = f2bf(gx); o.y = f2bf(gy);
        *(ushort2*)(zb + v * 384) = o;
    }
}

// ---------------- final (register-streamed, round-11 form): mix2 + bias + LN + residual + gate ----------------
// block = 256 threads = one batch, thread owns 2 d-cols. acc in regs (VGPR ~56 -> 8 waves/SIMD),
// coefficients DIRECT from uniform global pointer (SGPR invariant), tiny LDS for LN reduce.
__global__ __launch_bounds__(256) void final_kernel(const unsigned short* __restrict__ h2,
                                                    const float* __restrict__ x,
                                                    const float* __restrict__ bone,
                                                    const float* __restrict__ M2,
                                                    const float* __restrict__ coef,
                                                    const float* __restrict__ bias2,
                                                    const float* __restrict__ g2,
                                                    const float* __restrict__ b2,
                                                    float* __restrict__ out) {
    __shared__ float gate[17];
    __shared__ float red[17][8];    // [v][wave]=sum, [v][4+wave]=sumsq
    const int t = threadIdx.x, lane = t & 63, wave = t >> 6;
    const int d0 = t * 2;
    const long b = blockIdx.x;

    #pragma unroll
    for (int v0 = 0; v0 < 20; v0 += 4) {
        int v = v0 + wave;
        if (v < 17) {
            float s = bone[(b * 17 + v) * 192 + lane];
            #pragma unroll
            for (int off = 32; off; off >>= 1) s += __shfl_xor(s, off);
            if (lane == 0) gate[v] = 1.f / (1.f + expf(-s * (0.01f / 64.f)));
        }
    }

    const unsigned short* hb = h2 + b * 17 * 1024;
    float ax[17], ay[17];
    const float bx = bias2[d0], by = bias2[d0 + 1];
    #pragma unroll
    for (int v = 0; v < 17; ++v) {
        float dg = coef[289 + v];
        float2 m = *(const float2*)(M2 + v * 512 + d0);
        ushort2 hv = *(const ushort2*)(hb + v * 1024 + d0);
        ax[v] = dg * m.x * frombf(hv.x) + bx;
        ay[v] = dg * m.y * frombf(hv.y) + by;
    }
    #pragma unroll
    for (int w = 0; w < 17; ++w) {
        float2 m = *(const float2*)(M2 + w * 512 + d0);
        ushort2 hw = *(const ushort2*)(hb + w * 1024 + 512 + d0);
        float px = m.x * frombf(hw.x);
        float py = m.y * frombf(hw.y);
        #pragma unroll
        for (int v = 0; v < 17; ++v) {
            float c = coef[v * 17 + w];     // uniform -> s_load, SGPR operand
            ax[v] += c * px;
            ay[v] += c * py;
        }
    }
    #pragma unroll
    for (int v = 0; v < 17; ++v) {
        float s = ax[v] + ay[v];
        float q = ax[v] * ax[v] + ay[v] * ay[v];
        #pragma unroll
        for (int off = 32; off; off >>= 1) { s += __shfl_xor(s, off); q += __shfl_xor(q, off); }
        if (lane == 0) { red[v][wave] = s; red[v][4 + wave] = q; }
    }
    __syncthreads();
    const float2 gg = *(const float2*)(g2 + d0);
    const float2 bb = *(const float2*)(b2 + d0);
    const float* xb = x + b * 17 * 512 + d0;
    float* ob = out + b * 17 * 512 + d0;
    #pragma unroll
    for (int v = 0; v < 17; ++v) {
        float s = red[v][0] + red[v][1] + red[v][2] + red[v][3];
        float q = red[v][4] + red[v][5] + red[v][6] + red[v][7];
        float mean = s * (1.f / 512.f);
        float rstd = rsqrtf(q * (1.f / 512.f) - mean * mean + 1e-5f);
        const bool endj = (v == 3 || v == 6 || v == 10 || v == 13 || v == 16);
        float scale = endj ? (1.f + 0.03f * gate[v]) : 1.f;
        float2 xv = *(const float2*)(xb + v * 512);
        float ox = (xv.x + (ax[v] - mean) * rstd * gg.x + bb.x) * scale;
        float oy = (xv.y + (ay[v] - mean) * rstd * gg.y + bb.y) * scale;
        *(float2*)(ob + v * 512) = make_float2(ox, oy);
    }
}

// ---------------- launch ----------------
extern "C" void kernel_launch(void* const* d_in, const int* in_sizes, int n_in,
                              void* d_out, int out_size, void* d_ws, size_t ws_size,
                              hipStream_t stream) {
    const float* x     = (const float*)d_in[0];
    const float* bone  = (const float*)d_in[1];
    const float* adj   = (const float*)d_in[2];
    const float* g1    = (const float*)d_in[3];
    const float* b1    = (const float*)d_in[4];
    const float* W1    = (const float*)d_in[5];
    const float* M1    = (const float*)d_in[6];
    const float* A21   = (const float*)d_in[7];
    const float* bias1 = (const float*)d_in[8];
    const float* W2    = (const float*)d_in[9];
    const float* M2    = (const float*)d_in[10];
    const float* A22   = (const float*)d_in[11];
    const float* bias2 = (const float*)d_in[12];
    const float* g2    = (const float*)d_in[13];
    const float* b2    = (const float*)d_in[14];
    float* out = (float*)d_out;

    char* ws = (char*)d_ws;
    size_t off = 0;
    auto alloc = [&](size_t bytes) -> char* {
        char* p = ws + off;
        off = (off + bytes + 255) & ~(size_t)255;
        return p;
    };
    unsigned short* w1t = (unsigned short*)alloc(768 * 512 * 2);
    unsigned short* w2t = (unsigned short*)alloc(1024 * 384 * 2);
    float* coef1 = (float*)alloc(306 * 4);
    float* coef2 = (float*)alloc(306 * 4);
    size_t fixed = off;

    int nc = 32;
    const int cands[6] = {1, 2, 4, 8, 16, 32};
    for (int ci = 0; ci < 6; ++ci) {
        size_t Bc = 8192 / cands[ci];
        size_t need = fixed + Bc * 17 * (512 + 768 + 384 + 1024) * 2 + 4 * 256;
        if (need <= ws_size) { nc = cands[ci]; break; }
    }
    long Bc = 8192 / nc;
    unsigned short* y  = (unsigned short*)alloc(Bc * 17 * 512 * 2);
    unsigned short* h  = (unsigned short*)alloc(Bc * 17 * 768 * 2);
    unsigned short* z  = (unsigned short*)alloc(Bc * 17 * 384 * 2);
    unsigned short* h2 = (unsigned short*)alloc(Bc * 17 * 1024 * 2);

    prep_w1<<<(768 * 512 + 255) / 256, 256, 0, stream>>>(W1, w1t);
    prep_w2<<<(1024 * 384 + 255) / 256, 256, 0, stream>>>(W2, w2t);
    prep_adj<<<1, 320, 0, stream>>>(adj, A21, A22, coef1, coef2);

    int rows = (int)(Bc * 17);
    int nby = rows / 256;
    for (int c = 0; c < nc; ++c) {
        long rb = (long)c * rows;
        ln1_kernel<<<rows / 4, 256, 0, stream>>>(x + rb * 512, g1, b1, y, rows);
        gemm_bt_kernel<<<6 * nby, 512, 0, stream>>>(y, w1t, h, 512, 768, 6);
        mixgelu_kernel<<<Bc / 2, 384, 0, stream>>>(h, M1, coef1, bias1, z);
        gemm_bt_kernel<<<8 * nby, 512, 0, stream>>>(z, w2t, h2, 384, 1024, 8);
        final_kernel<<<Bc, 256, 0, stream>>>(h2, x + rb * 512, bone + rb * 192, M2, coef2,
                                             bias2, g2, b2, out + rb * 512);
    }
}